// Round 1
// baseline (45.490 us; speedup 1.0000x reference)
//
#include <hip/hip_runtime.h>

#define BATCH 64
#define NGT 8
#define DIMT 10647
#define NCLS 20
#define EPS16 6.103515625e-05f

// ---------------------------------------------------------------------------
// Kernel 1: dense sum of sigmoid(pconf)^2 over all BATCH*DIMT elements -> ws[0]
// ---------------------------------------------------------------------------
__global__ __launch_bounds__(256) void confsum_kernel(const float* __restrict__ pconf,
                                                      double* __restrict__ ws, int n4)
{
    const float4* p4 = reinterpret_cast<const float4*>(pconf);
    float acc = 0.0f;
    for (int i = blockIdx.x * blockDim.x + threadIdx.x; i < n4; i += gridDim.x * blockDim.x) {
        float4 v = p4[i];
        float s0 = 1.0f / (1.0f + expf(-v.x));
        float s1 = 1.0f / (1.0f + expf(-v.y));
        float s2 = 1.0f / (1.0f + expf(-v.z));
        float s3 = 1.0f / (1.0f + expf(-v.w));
        acc += s0 * s0 + s1 * s1 + s2 * s2 + s3 * s3;
    }
    // wave reduce (wave = 64)
    for (int off = 32; off > 0; off >>= 1) acc += __shfl_down(acc, off);
    __shared__ float lds[4];
    int wid = threadIdx.x >> 6, lane = threadIdx.x & 63;
    if (lane == 0) lds[wid] = acc;
    __syncthreads();
    if (threadIdx.x == 0) {
        float s = lds[0] + lds[1] + lds[2] + lds[3];
        atomicAdd(&ws[0], (double)s);
    }
}

// ---------------------------------------------------------------------------
// Kernel 2: per-image match (analytic replay of the scan) + sparse loss terms.
// One block per image, 64 threads (= 1 wave). Candidate slot u = i*9 + s*3 + a.
//   ws[1] += sum over affected cells of sigmoid(pconf)^2
//   ws[2] += sum over pos cells of (sigmoid(pconf)-1)^2
//   ws[3] += #pos ; ws[4] += #affected(distinct)
//   ws[5] += cls_sum/clip(npos) ; ws[6] += txty/clip ; ws[7] += twth/clip
// ---------------------------------------------------------------------------
__global__ __launch_bounds__(64) void match_kernel(const float* __restrict__ pconf,
                                                   const float* __restrict__ pcls,
                                                   const float* __restrict__ ptxywh,
                                                   const float* __restrict__ gboxes,
                                                   const int* __restrict__ glabels,
                                                   double* __restrict__ ws)
{
    const int b = blockIdx.x;
    const int t = threadIdx.x;

    __shared__ int   s_base[NGT][3];
    __shared__ float s_txyx[NGT][3], s_txyy[NGT][3];
    __shared__ float s_w[NGT], s_h[NGT], s_wt[NGT];
    __shared__ int   s_lab[NGT], s_ids[NGT];
    __shared__ int   s_cand[72];

    const float ax[9] = {0.025f, 0.04f, 0.08f, 0.07f, 0.15f, 0.14f, 0.28f, 0.38f, 0.9f};
    const float ay[9] = {0.033f, 0.07f, 0.06f, 0.15f, 0.11f, 0.29f, 0.22f, 0.48f, 0.78f};
    const int grids[3] = {52, 26, 13};
    const int coff[3]  = {0, 2704, 3380};

    if (t < NGT) {
        int i = t;
        float l  = gboxes[(b * NGT + i) * 4 + 0];
        float tp = gboxes[(b * NGT + i) * 4 + 1];
        float r  = gboxes[(b * NGT + i) * 4 + 2];
        float bt = gboxes[(b * NGT + i) * 4 + 3];
        float cx = (l + r) * 0.5f, cy = (tp + bt) * 0.5f;
        float w = r - l, h = bt - tp;
        s_w[i] = w; s_h[i] = h; s_wt[i] = 2.0f - w * h;
        s_lab[i] = glabels[b * NGT + i] - 1;
        float whp = w * h;
        float best = -1.0f; int bi = 0;
        for (int a = 0; a < 9; a++) {
            float inter = fminf(w, ax[a]) * fminf(h, ay[a]);
            float iou = inter / (whp + ax[a] * ay[a] - inter);
            if (iou > best) { best = iou; bi = a; }
        }
        s_ids[i] = bi;
        for (int s = 0; s < 3; s++) {
            float gf = (float)grids[s];
            int col = (int)(cx * gf);
            int row = (int)(cy * gf);
            s_base[i][s] = (coff[s] + row * grids[s] + col) * 3;
            s_txyx[i][s] = (cx - (float)col / gf) * gf;
            s_txyy[i][s] = (cy - (float)row / gf) * gf;
        }
    }
    __syncthreads();

    {
        int u = t;              // slots 0..63
        int i = u / 9, r = u % 9;
        s_cand[u] = s_base[i][r / 3] + (r % 3);
    }
    if (t < 8) {                // slots 64..71
        int u = t + 64;
        int i = u / 9, r = u % 9;
        s_cand[u] = s_base[i][r / 3] + (r % 3);
    }
    __syncthreads();

    float np_loc = 0.f, naff_loc = 0.f, bsig_loc = 0.f, cpos_loc = 0.f;
    float cls_loc = 0.f, txty_loc = 0.f, twth_loc = 0.f;

    for (int rep = 0; rep < 2; ++rep) {
        int u = t + rep * 64;
        if (u < 72) {
            int d = s_cand[u];
            // dedupe (canonical = first slot with this d) + last neg box index
            bool canon = true;
            int lastneg_i = -1;
            for (int v = 0; v < 72; ++v) {
                if (s_cand[v] == d) {
                    if (v < u) canon = false;
                    int iv = v / 9;
                    if (iv > lastneg_i) lastneg_i = iv;
                }
            }
            if (canon) {
                naff_loc += 1.0f;
                int negtag = lastneg_i * 16 + 14;   // last neg write: step (i, j=7), tag 2k
                // scan pos events (i,j): pos_idx = base[i][ceng[j]] + ancoff[j], tag 2k+1
                int best_tag = -1, bi = -1, bj = -1;
                for (int i = 0; i < NGT; i++) {
                    for (int j = 0; j < NGT; j++) {
                        int s = s_ids[j] / 3, a = s_ids[j] % 3;
                        int pd = s_base[i][s] + a;
                        if (pd == d) {
                            int tag = i * 16 + j * 2 + 1;
                            if (tag > best_tag) { best_tag = tag; bi = i; bj = j; }
                        }
                    }
                }
                float pc = pconf[b * DIMT + d];
                float sg = 1.0f / (1.0f + expf(-pc));
                bsig_loc += sg * sg;
                if (best_tag > negtag) {
                    // final state is a pos row written by event (bi, bj)
                    np_loc += 1.0f;
                    cpos_loc += (sg - 1.0f) * (sg - 1.0f);
                    int lab = s_lab[bi];
                    float wt = s_wt[bi];
                    int aidx = s_ids[bj];
                    int s = aidx / 3;
                    float tx = s_txyx[bi][s], ty = s_txyy[bi][s];
                    float twx = logf(s_w[bi] / ax[aidx]);
                    float twy = logf(s_h[bi] / ay[aidx]);
                    // class BCE over 20 logits vs onehot(lab)
                    const float* pc20 = &pcls[(size_t)(b * DIMT + d) * NCLS];
                    float cs = 0.0f;
                    for (int c = 0; c < NCLS; c++) {
                        float x = pc20[c];
                        float tt = (c == lab) ? 1.0f : 0.0f;
                        cs += fmaxf(x, 0.0f) - x * tt + log1pf(expf(-fabsf(x)));
                    }
                    cls_loc += cs;
                    const float* pt = &ptxywh[(size_t)(b * DIMT + d) * 4];
                    float x0 = pt[0], x1 = pt[1];
                    float bce0 = fmaxf(x0, 0.0f) - x0 * tx + log1pf(expf(-fabsf(x0)));
                    float bce1 = fmaxf(x1, 0.0f) - x1 * ty + log1pf(expf(-fabsf(x1)));
                    txty_loc += (bce0 + bce1) * wt;
                    float d2 = (pt[2] - twx) * (pt[2] - twx) + (pt[3] - twy) * (pt[3] - twy);
                    twth_loc += d2 * wt;
                }
            }
        }
    }

    // single-wave reduce (block = 64 threads)
    for (int off = 32; off > 0; off >>= 1) {
        np_loc   += __shfl_down(np_loc, off);
        naff_loc += __shfl_down(naff_loc, off);
        bsig_loc += __shfl_down(bsig_loc, off);
        cpos_loc += __shfl_down(cpos_loc, off);
        cls_loc  += __shfl_down(cls_loc, off);
        txty_loc += __shfl_down(txty_loc, off);
        twth_loc += __shfl_down(twth_loc, off);
    }
    if (t == 0) {
        float npos_c = fmaxf(np_loc, EPS16);
        atomicAdd(&ws[1], (double)bsig_loc);
        atomicAdd(&ws[2], (double)cpos_loc);
        atomicAdd(&ws[3], (double)np_loc);
        atomicAdd(&ws[4], (double)naff_loc);
        atomicAdd(&ws[5], (double)(cls_loc / npos_c));
        atomicAdd(&ws[6], (double)(txty_loc / npos_c));
        atomicAdd(&ws[7], (double)(twth_loc / npos_c));
    }
}

// ---------------------------------------------------------------------------
// Kernel 3: combine accumulators into the scalar loss.
// ---------------------------------------------------------------------------
__global__ void final_kernel(const double* __restrict__ ws, float* __restrict__ out)
{
    double A  = ws[0];   // sum sig^2 over all
    double Bs = ws[1];   // sum sig^2 over affected
    double C  = ws[2];   // sum (sig-1)^2 over pos
    double Np = ws[3];   // total pos count
    double Na = ws[4];   // total affected count
    double tot = (double)BATCH * (double)DIMT;
    double lcp  = C / fmax(Np, (double)EPS16) * 30.0;
    double lcn  = (A - Bs) / fmax(tot - Na, (double)EPS16) * 30.0;
    double lcls = ws[5] / (double)BATCH;
    double ltxty = ws[6] / (double)BATCH;
    double ltwth = ws[7] / (double)BATCH;
    out[0] = (float)(lcp + lcn + lcls + ltxty + ltwth);
}

extern "C" void kernel_launch(void* const* d_in, const int* in_sizes, int n_in,
                              void* d_out, int out_size, void* d_ws, size_t ws_size,
                              hipStream_t stream)
{
    const float* pconf = (const float*)d_in[0];
    const float* pcls  = (const float*)d_in[1];
    const float* ptxy  = (const float*)d_in[2];
    const float* gbox  = (const float*)d_in[3];
    const int*   glab  = (const int*)d_in[4];
    double* ws = (double*)d_ws;

    hipMemsetAsync(d_ws, 0, 8 * sizeof(double), stream);

    const int n4 = (BATCH * DIMT) / 4;   // 681408 / 4 = 170352, exact
    confsum_kernel<<<512, 256, 0, stream>>>(pconf, ws, n4);
    match_kernel<<<BATCH, 64, 0, stream>>>(pconf, pcls, ptxy, gbox, glab, ws);
    final_kernel<<<1, 1, 0, stream>>>(ws, (float*)d_out);
}

// Round 2
// 26.585 us; speedup vs baseline: 1.7111x; 1.7111x over previous
//
#include <hip/hip_runtime.h>

#define BATCH 64
#define NGT 8
#define DIMT 10647
#define NCLS 20
#define EPS16 6.103515625e-05f

// ws layout (doubles):
//   [b*8 + 0..6]  per-image match partials, b in [0,64):
//                 0: sum sig^2 over affected cells
//                 1: sum (sig-1)^2 over pos cells
//                 2: #pos
//                 3: #affected (distinct)
//                 4: cls_sum   / clip(npos)
//                 5: txty_sum  / clip(npos)
//                 6: twth_sum  / clip(npos)
//   [512 + j]     confsum partial of block j, j in [0,448)
// All slots written unconditionally every call -> no init needed.
#define WS_CONF_OFF 512
#define NCB 448              // confsum blocks
#define GRID_A (BATCH + NCB) // 512

__global__ __launch_bounds__(256) void fused_kernel(const float* __restrict__ pconf,
                                                    const float* __restrict__ pcls,
                                                    const float* __restrict__ ptxywh,
                                                    const float* __restrict__ gboxes,
                                                    const int* __restrict__ glabels,
                                                    double* __restrict__ ws)
{
    const int t = threadIdx.x;

    if (blockIdx.x >= BATCH) {
        // ---------------- confsum role: sum sigmoid(pconf)^2 ----------------
        const int cb = blockIdx.x - BATCH;      // 0..NCB-1
        const int n4 = (BATCH * DIMT) / 4;      // 170352, exact
        const float4* p4 = reinterpret_cast<const float4*>(pconf);
        float acc = 0.0f;
        for (int i = cb * 256 + t; i < n4; i += NCB * 256) {
            float4 v = p4[i];
            float s0 = 1.0f / (1.0f + expf(-v.x));
            float s1 = 1.0f / (1.0f + expf(-v.y));
            float s2 = 1.0f / (1.0f + expf(-v.z));
            float s3 = 1.0f / (1.0f + expf(-v.w));
            acc += s0 * s0 + s1 * s1 + s2 * s2 + s3 * s3;
        }
        for (int off = 32; off > 0; off >>= 1) acc += __shfl_down(acc, off);
        __shared__ float lds[4];
        int wid = t >> 6, lane = t & 63;
        if (lane == 0) lds[wid] = acc;
        __syncthreads();
        if (t == 0) ws[WS_CONF_OFF + cb] = (double)(lds[0] + lds[1] + lds[2] + lds[3]);
        return;
    }

    // ------------------------- match role: one image --------------------------
    const int b = blockIdx.x;

    __shared__ int   s_base[NGT][3];
    __shared__ float s_txyx[NGT][3], s_txyy[NGT][3];
    __shared__ float s_w[NGT], s_h[NGT], s_wt[NGT];
    __shared__ int   s_lab[NGT], s_ids[NGT];
    __shared__ int   s_cand[72];

    const float ax[9] = {0.025f, 0.04f, 0.08f, 0.07f, 0.15f, 0.14f, 0.28f, 0.38f, 0.9f};
    const float ay[9] = {0.033f, 0.07f, 0.06f, 0.15f, 0.11f, 0.29f, 0.22f, 0.48f, 0.78f};
    const int grids[3] = {52, 26, 13};
    const int coff[3]  = {0, 2704, 3380};

    if (t < NGT) {
        int i = t;
        float l  = gboxes[(b * NGT + i) * 4 + 0];
        float tp = gboxes[(b * NGT + i) * 4 + 1];
        float r  = gboxes[(b * NGT + i) * 4 + 2];
        float bt = gboxes[(b * NGT + i) * 4 + 3];
        float cx = (l + r) * 0.5f, cy = (tp + bt) * 0.5f;
        float w = r - l, h = bt - tp;
        s_w[i] = w; s_h[i] = h; s_wt[i] = 2.0f - w * h;
        s_lab[i] = glabels[b * NGT + i] - 1;
        float whp = w * h;
        float best = -1.0f; int bi = 0;
        for (int a = 0; a < 9; a++) {
            float inter = fminf(w, ax[a]) * fminf(h, ay[a]);
            float iou = inter / (whp + ax[a] * ay[a] - inter);
            if (iou > best) { best = iou; bi = a; }
        }
        s_ids[i] = bi;
        for (int s = 0; s < 3; s++) {
            float gf = (float)grids[s];
            int col = (int)(cx * gf);
            int row = (int)(cy * gf);
            s_base[i][s] = (coff[s] + row * grids[s] + col) * 3;
            s_txyx[i][s] = (cx - (float)col / gf) * gf;
            s_txyy[i][s] = (cy - (float)row / gf) * gf;
        }
    }
    __syncthreads();

    if (t < 72) {
        int i = t / 9, r = t % 9;
        s_cand[t] = s_base[i][r / 3] + (r % 3);
    }
    __syncthreads();

    float np_loc = 0.f, naff_loc = 0.f, bsig_loc = 0.f, cpos_loc = 0.f;
    float cls_loc = 0.f, txty_loc = 0.f, twth_loc = 0.f;

    if (t < 72) {
        int d = s_cand[t];
        // dedupe (canonical = first slot with this d) + last neg-writing box
        bool canon = true;
        int lastneg_i = -1;
        for (int v = 0; v < 72; ++v) {
            if (s_cand[v] == d) {
                if (v < t) canon = false;
                int iv = v / 9;
                if (iv > lastneg_i) lastneg_i = iv;
            }
        }
        if (canon) {
            naff_loc = 1.0f;
            int negtag = lastneg_i * 16 + 14;   // last neg write: step (i, j=7), tag 2k
            // scan pos events (i,j): pos_idx = base[i][ceng[j]] + ancoff[j], tag 2k+1
            int best_tag = -1, bi = -1, bj = -1;
            for (int i = 0; i < NGT; i++) {
                for (int j = 0; j < NGT; j++) {
                    int s = s_ids[j] / 3, a = s_ids[j] % 3;
                    int pd = s_base[i][s] + a;
                    if (pd == d) {
                        int tag = i * 16 + j * 2 + 1;
                        if (tag > best_tag) { best_tag = tag; bi = i; bj = j; }
                    }
                }
            }
            float pc = pconf[b * DIMT + d];
            float sg = 1.0f / (1.0f + expf(-pc));
            bsig_loc = sg * sg;
            if (best_tag > negtag) {
                // final state: pos row written by event (bi, bj)
                np_loc = 1.0f;
                cpos_loc = (sg - 1.0f) * (sg - 1.0f);
                int lab = s_lab[bi];
                float wt = s_wt[bi];
                int aidx = s_ids[bj];
                int s = aidx / 3;
                float tx = s_txyx[bi][s], ty = s_txyy[bi][s];
                float twx = logf(s_w[bi] / ax[aidx]);
                float twy = logf(s_h[bi] / ay[aidx]);
                const float* pc20 = &pcls[(size_t)(b * DIMT + d) * NCLS];
                float cs = 0.0f;
                for (int c = 0; c < NCLS; c++) {
                    float x = pc20[c];
                    float tt = (c == lab) ? 1.0f : 0.0f;
                    cs += fmaxf(x, 0.0f) - x * tt + log1pf(expf(-fabsf(x)));
                }
                cls_loc = cs;
                const float* pt = &ptxywh[(size_t)(b * DIMT + d) * 4];
                float x0 = pt[0], x1 = pt[1];
                float bce0 = fmaxf(x0, 0.0f) - x0 * tx + log1pf(expf(-fabsf(x0)));
                float bce1 = fmaxf(x1, 0.0f) - x1 * ty + log1pf(expf(-fabsf(x1)));
                txty_loc = (bce0 + bce1) * wt;
                float d2 = (pt[2] - twx) * (pt[2] - twx) + (pt[3] - twy) * (pt[3] - twy);
                twth_loc = d2 * wt;
            }
        }
    }

    // block reduce 7 floats (active threads live in waves 0/1 of 4)
    for (int off = 32; off > 0; off >>= 1) {
        np_loc   += __shfl_down(np_loc, off);
        naff_loc += __shfl_down(naff_loc, off);
        bsig_loc += __shfl_down(bsig_loc, off);
        cpos_loc += __shfl_down(cpos_loc, off);
        cls_loc  += __shfl_down(cls_loc, off);
        txty_loc += __shfl_down(txty_loc, off);
        twth_loc += __shfl_down(twth_loc, off);
    }
    __shared__ float red[4][7];
    {
        int wid = t >> 6, lane = t & 63;
        if (lane == 0) {
            red[wid][0] = bsig_loc; red[wid][1] = cpos_loc; red[wid][2] = np_loc;
            red[wid][3] = naff_loc; red[wid][4] = cls_loc;  red[wid][5] = txty_loc;
            red[wid][6] = twth_loc;
        }
    }
    __syncthreads();
    if (t == 0) {
        float v[7];
        for (int k = 0; k < 7; k++) v[k] = red[0][k] + red[1][k] + red[2][k] + red[3][k];
        float npos_c = fmaxf(v[2], EPS16);
        ws[b * 8 + 0] = (double)v[0];
        ws[b * 8 + 1] = (double)v[1];
        ws[b * 8 + 2] = (double)v[2];
        ws[b * 8 + 3] = (double)v[3];
        ws[b * 8 + 4] = (double)(v[4] / npos_c);
        ws[b * 8 + 5] = (double)(v[5] / npos_c);
        ws[b * 8 + 6] = (double)(v[6] / npos_c);
    }
}

// ---------------------------------------------------------------------------
// Kernel 2: reduce all partials, combine into the scalar loss.
// ---------------------------------------------------------------------------
__global__ __launch_bounds__(512) void final_kernel(const double* __restrict__ ws,
                                                    float* __restrict__ out)
{
    const int t = threadIdx.x;
    double a = (t < NCB) ? ws[WS_CONF_OFF + t] : 0.0;
    for (int off = 32; off > 0; off >>= 1) a += __shfl_down(a, off);
    __shared__ double lds[8];
    if ((t & 63) == 0) lds[t >> 6] = a;
    __syncthreads();

    // per-image partials: wave 0, lane = image
    double v0 = 0, v1 = 0, v2 = 0, v3 = 0, v4 = 0, v5 = 0, v6 = 0;
    if (t < 64) {
        v0 = ws[t * 8 + 0]; v1 = ws[t * 8 + 1]; v2 = ws[t * 8 + 2];
        v3 = ws[t * 8 + 3]; v4 = ws[t * 8 + 4]; v5 = ws[t * 8 + 5];
        v6 = ws[t * 8 + 6];
        for (int off = 32; off > 0; off >>= 1) {
            v0 += __shfl_down(v0, off); v1 += __shfl_down(v1, off);
            v2 += __shfl_down(v2, off); v3 += __shfl_down(v3, off);
            v4 += __shfl_down(v4, off); v5 += __shfl_down(v5, off);
            v6 += __shfl_down(v6, off);
        }
    }
    if (t == 0) {
        double A = lds[0] + lds[1] + lds[2] + lds[3] + lds[4] + lds[5] + lds[6] + lds[7];
        double tot = (double)BATCH * (double)DIMT;
        double lcp  = v1 / fmax(v2, (double)EPS16) * 30.0;
        double lcn  = (A - v0) / fmax(tot - v3, (double)EPS16) * 30.0;
        double lcls  = v4 / (double)BATCH;
        double ltxty = v5 / (double)BATCH;
        double ltwth = v6 / (double)BATCH;
        out[0] = (float)(lcp + lcn + lcls + ltxty + ltwth);
    }
}

extern "C" void kernel_launch(void* const* d_in, const int* in_sizes, int n_in,
                              void* d_out, int out_size, void* d_ws, size_t ws_size,
                              hipStream_t stream)
{
    const float* pconf = (const float*)d_in[0];
    const float* pcls  = (const float*)d_in[1];
    const float* ptxy  = (const float*)d_in[2];
    const float* gbox  = (const float*)d_in[3];
    const int*   glab  = (const int*)d_in[4];
    double* ws = (double*)d_ws;

    fused_kernel<<<GRID_A, 256, 0, stream>>>(pconf, pcls, ptxy, gbox, glab, ws);
    final_kernel<<<1, 512, 0, stream>>>(ws, (float*)d_out);
}